// Round 2
// baseline (627.413 us; speedup 1.0000x reference)
//
#include <hip/hip_runtime.h>
#include <stdint.h>

// LiquidStateMachine on MI355X — round 20.
// r19 post-mortem: total 326->617us. The regression was lsm_fill (8 blk x
// 64 thr walking W COLUMN-strided: 256K uncoalesced lines, 8 CUs -> 300us
// serial). lsm_main counters were polluted (31ms/70MB profiled dispatch is
// a replay artifact); whether the schedule helps is STILL UNMEASURED.
// r20 makes it measurable:
//  (a) lsm_fill v2: 8 blk x 512 thr. Phase 1 sweeps W ROW-major coalesced
//      (thread t owns column t), buckets nonzeros by cluster k&7 into LDS,
//      weights -> LDS wlist (entry = k<<7|widx; phase 3 never reads W).
//      Phase 2 (per-slot cap-8 LPT assignment) runs on wave 0 only, NO
//      barriers (single-wave DS ops are in-order; atomic returns wait).
//      Pads pick the slot's LEAST-loaded cluster (argmin cap), encoded
//      0xFFE0|r. Phase 3: coalesced 1KB/2KB chunk emission. ~300 -> ~15us,
//      deterministic (one writer/column, k-ascending).
//  (b) I-dot reverted to r18's LDS-staged rl (proven 262us; r19's uniform-
//      global variant is the FETCH-anomaly suspect). Only delta vs r18 in
//      lsm_main's inputs is the scheduled gather stream.
// Weights EXACT fp32 (r2: rounding flips spikes); f16 spike 0/1 exact.
//
// d_ws layout (bytes):
//   0      PERM[512]  sorted-rank -> column
//   2048   RANK[512]  column -> sorted rank
//   4096   CNT[512]   nnz per column          (zeroed via hipMemsetAsync)
//   8192   CNTW[8]    per-group padded trip count (multiple of 8)
//   8256   IBASE[8]   per-group byte base into IDX region
//   8320   WBASE[8]   per-group byte base into WT region
//   16384  IDX        u16 spike-offset (16k):
//                     byte = ib + (j>>3)*1024 + lane*16 + (j&7)*2
//   81920  WT         f32 w: byte = wb + (j>>3)*2048 + lane*32 + (j&7)*4

#define N_NEU 512
#define B_ROWS 2048
#define D_IN 256
#define R_PB 8
#define NBLK (B_ROWS / R_PB)   // 256 blocks x 512 threads = 1 block/CU

#define WS_PERM    0
#define WS_RANK    2048
#define WS_CNT     4096
#define WS_CNTW    8192
#define WS_IBASE   8256
#define WS_WBASE   8320
#define WS_IDX     16384
#define WS_WT      81920

// spike record: 16 bytes (8 rows x f16 0/1) at natural offset 16k
#define SPK_OFF(k)  ((k) << 4)
#define SPK_BUF     8192       // one buffer: 512 neurons x 16 B

#define H16_ONE 0x3C00u        // f16 1.0
#define MAXPC   24             // max entries per (column, cluster); mean 6.4

// ---------------------------------------------------------------- prep A
__global__ __launch_bounds__(256) void lsm_count(
    const float* __restrict__ W, uint32_t* __restrict__ ws)
{
    int t  = threadIdx.x;
    int k0 = blockIdx.x * 4;
    int c0 = 0, c1 = 0;
    #pragma unroll
    for (int kk = 0; kk < 4; ++kk) {
        const float* row = W + (size_t)(k0 + kk) * N_NEU;
        c0 += (row[t]       != 0.0f) ? 1 : 0;
        c1 += (row[t + 256] != 0.0f) ? 1 : 0;
    }
    if (c0) atomicAdd(&ws[(WS_CNT >> 2) + t],       (uint32_t)c0);
    if (c1) atomicAdd(&ws[(WS_CNT >> 2) + t + 256], (uint32_t)c1);
}

// ---------------------------------------------------------------- prep B
__global__ __launch_bounds__(512) void lsm_sort(uint32_t* __restrict__ ws)
{
    __shared__ int hist[N_NEU + 1];
    __shared__ int csort[N_NEU];
    __shared__ int gcw[8];

    int t = threadIdx.x;
    int creal = (int)ws[(WS_CNT >> 2) + t];
    for (int i = t; i < N_NEU + 1; i += 512) hist[i] = 0;
    __syncthreads();
    atomicAdd(&hist[creal], 1);
    __syncthreads();
    if (t == 0) {
        int acc = 0;
        for (int v = 0; v <= N_NEU; ++v) { int h = hist[v]; hist[v] = acc; acc += h; }
    }
    __syncthreads();
    int rank = atomicAdd(&hist[creal], 1);
    ws[(WS_PERM >> 2) + rank] = (uint32_t)t;
    ws[(WS_RANK >> 2) + t]    = (uint32_t)rank;
    csort[rank] = creal;
    __syncthreads();
    if (t < 8) {
        int cw = csort[t * 64 + 63];         // ascending -> group max is last
        cw = (cw + 7) & ~7;                  // pad to multiple of 8 (one chunk)
        gcw[t] = cw;
        ws[(WS_CNTW >> 2) + t] = (uint32_t)cw;
    }
    __syncthreads();
    if (t == 0) {
        int ai = 0, aw = 0;
        for (int g = 0; g < 8; ++g) {
            ws[(WS_IBASE >> 2) + g] = (uint32_t)ai;
            ws[(WS_WBASE >> 2) + g] = (uint32_t)aw;
            ai += gcw[g] * 64 * 2;           // bytes (u16 per entry)
            aw += gcw[g] * 64 * 4;           // bytes (f32 per entry)
        }
    }
    // scheduler in lsm_fill writes EVERY slot (pads interleaved) — no tail pad
}

// ---------------------------------------------------------------- prep C
// One block per GROUP (8 blocks x 512 threads). Thread t owns column t:
// coalesced row-major sweep of W, bucket nonzero k by cluster k&7 into LDS.
// Wave 0 then builds the per-slot cap-8 LPT schedule (no barriers needed:
// single-wave DS ops are in-order). All 512 threads emit coalesced streams.
__global__ __launch_bounds__(512) void lsm_fill(
    const float* __restrict__ W, uint32_t* __restrict__ ws)
{
    int wg = blockIdx.x;            // 8 groups
    int t  = threadIdx.x;           // 512
    char* base = (char*)ws;

    __shared__ unsigned short ent[64][8][MAXPC];   // 24576 B: (k<<7|widx)
    __shared__ float          wlist[64][96];       // 24576 B: weights, k-order
    __shared__ unsigned short sched[64][96];       // 12288 B
    __shared__ unsigned char  entc[64][8];         //   512 B: bucket counts
    __shared__ int cap[8];

    int cw = (int)ws[(WS_CNTW >> 2) + wg];         // block-uniform, mult of 8
    uint32_t ib = ws[(WS_IBASE >> 2) + wg];
    uint32_t wb = ws[(WS_WBASE >> 2) + wg];

    // ---- phase 1: coalesced discovery (thread t = column t) ----
    int rank = (int)ws[(WS_RANK >> 2) + t];
    int ls   = rank & 63;
    bool mine = ((rank >> 6) == wg);
    unsigned cl = 0, ch = 0;        // packed per-cluster counters
    int wi = 0;                     // within-column weight index (k-order)
    for (int k0 = 0; k0 < N_NEU; k0 += 8) {
        #pragma unroll
        for (int rr = 0; rr < 8; ++rr) {
            float wv = W[(size_t)(k0 + rr) * N_NEU + t];   // coalesced
            if (mine && wv != 0.0f) {
                unsigned cnt = ((rr < 4) ? (cl >> (rr * 8))
                                         : (ch >> ((rr - 4) * 8))) & 0xffu;
                ent[ls][rr][cnt] = (unsigned short)(((k0 + rr) << 7) | wi);
                wlist[ls][wi] = wv;
                if (rr < 4) cl += 1u << (rr * 8);
                else        ch += 1u << ((rr - 4) * 8);
                ++wi;
            }
        }
    }
    if (mine) {
        #pragma unroll
        for (int r = 0; r < 8; ++r)
            entc[ls][r] = (unsigned char)(((r < 4) ? (cl >> (r * 8))
                                                   : (ch >> ((r - 4) * 8))) & 0xffu);
    }
    __syncthreads();

    // ---- phase 2: wave-0-only per-slot assignment (no block barriers) ----
    if (t < 64) {
        int u = t;
        unsigned cl2 = 0, ch2 = 0; int tot = 0;
        #pragma unroll
        for (int r = 0; r < 8; ++r) {
            unsigned v = entc[u][r]; tot += (int)v;
            if (r < 4) cl2 |= v << (r * 8); else ch2 |= v << ((r - 4) * 8);
        }
        for (int j = 0; j < cw; ++j) {
            if (u < 8) cap[u] = 0;           // in-order DS: visible to claims
            int sel = -1;
            if (tot > 0) {
                int slack = (cw - j) - tot;
                unsigned tried = 0;
                for (int pass = 0; pass < 8 && sel < 0; ++pass) {
                    int best = -1; unsigned bv = 0;
                    #pragma unroll
                    for (int r = 0; r < 8; ++r) {
                        unsigned v = ((r < 4) ? (cl2 >> (r * 8))
                                              : (ch2 >> ((r - 4) * 8))) & 0xffu;
                        if (!((tried >> r) & 1u) && v > bv) { bv = v; best = r; }
                    }
                    if (best < 0) break;
                    int old = atomicAdd(&cap[best], 1);
                    if (old < 8) sel = best;
                    else { atomicSub(&cap[best], 1); tried |= (1u << best); }
                }
                if (sel < 0 && slack <= 0) { // zero slack: overflow (rare)
                    int best = 0; unsigned bv = 0;
                    #pragma unroll
                    for (int r = 0; r < 8; ++r) {
                        unsigned v = ((r < 4) ? (cl2 >> (r * 8))
                                              : (ch2 >> ((r - 4) * 8))) & 0xffu;
                        if (v > bv) { bv = v; best = r; }
                    }
                    sel = best;
                    atomicAdd(&cap[sel], 1); // keep cap honest for pad argmin
                }
            }
            unsigned short sv;
            if (sel >= 0) {
                unsigned v = ((sel < 4) ? (cl2 >> (sel * 8))
                                        : (ch2 >> ((sel - 4) * 8))) & 0xffu;
                sv = ent[u][sel][(int)v - 1];
                if (sel < 4) cl2 -= 1u << (sel * 8);
                else         ch2 -= 1u << ((sel - 4) * 8);
                --tot;
            } else {
                // pad: least-loaded cluster this slot (reads after claims:
                // program order within the wave). 0xFFE0|r > any real entry
                // (max real = (511<<7)|95 = 0xFFDF).
                int bestr = 0, bvv = 1 << 30;
                #pragma unroll
                for (int r = 0; r < 8; ++r) {
                    int v = cap[r]; if (v < bvv) { bvv = v; bestr = r; }
                }
                sv = (unsigned short)(0xFFE0u | (unsigned)bestr);
            }
            sched[u][j] = sv;
        }
    }
    __syncthreads();

    // ---- phase 3: coalesced emission (thread = (ls3, sub-slot js)) ----
    int ls3 = t >> 3, js = t & 7;
    for (int j = js; j < cw; j += 8) {       // j&7 == js
        unsigned sv = sched[ls3][j];
        unsigned short idxv; float wv;
        if (sv < 0xFFE0u) {
            idxv = (unsigned short)((sv >> 7) << 4);     // SPK_OFF(k)
            wv   = wlist[ls3][sv & 0x7Fu];
        } else {
            idxv = (unsigned short)((sv & 7u) << 4);     // pad: broadcast addr
            wv   = 0.0f;
        }
        *(unsigned short*)(base + WS_IDX + ib + (j >> 3) * 1024 + ls3 * 16 + js * 2) = idxv;
        *(float*)(base + WS_WT + wb + (j >> 3) * 2048 + ls3 * 32 + js * 4) = wv;
    }
}

// -------- spill-proof pipeline macros (all scalars, no arrays/fns) --------
// B = spike-buffer base for this step; offsets pre-scaled to 16k.
#define GATH(P, X, B) \
    P##0 = *(const uint4*)((B) + ((X).x & 0xffffu)); \
    P##1 = *(const uint4*)((B) + ((X).x >> 16));     \
    P##2 = *(const uint4*)((B) + ((X).y & 0xffffu)); \
    P##3 = *(const uint4*)((B) + ((X).y >> 16));     \
    P##4 = *(const uint4*)((B) + ((X).z & 0xffffu)); \
    P##5 = *(const uint4*)((B) + ((X).z >> 16));     \
    P##6 = *(const uint4*)((B) + ((X).w & 0xffffu)); \
    P##7 = *(const uint4*)((B) + ((X).w >> 16));

// mixed-precision FMA: acc(f32) += w(f32) * f16 half of S (lo/hi)
#define FMIX_LO(ACC, WV, S) \
    asm("v_fma_mix_f32 %0, %1, %2, %0 op_sel:[0,0,0] op_sel_hi:[0,1,0]" \
        : "+v"(ACC) : "v"(WV), "v"(S));
#define FMIX_HI(ACC, WV, S) \
    asm("v_fma_mix_f32 %0, %1, %2, %0 op_sel:[0,1,0] op_sel_hi:[0,1,0]" \
        : "+v"(ACC) : "v"(WV), "v"(S));

// one entry: weight WV x 8 rows' f16 spikes (uint4 S = 4 f16-pairs)
#define C1(S, WV) \
    FMIX_LO(rec0, WV, (S).x) FMIX_HI(rec1, WV, (S).x) \
    FMIX_LO(rec2, WV, (S).y) FMIX_HI(rec3, WV, (S).y) \
    FMIX_LO(rec4, WV, (S).z) FMIX_HI(rec5, WV, (S).z) \
    FMIX_LO(rec6, WV, (S).w) FMIX_HI(rec7, WV, (S).w)

#define CONS(P, WA, WB) \
    C1(P##0, (WA).x) C1(P##1, (WA).y) C1(P##2, (WA).z) C1(P##3, (WA).w) \
    C1(P##4, (WB).x) C1(P##5, (WB).y) C1(P##6, (WB).z) C1(P##7, (WB).w)

#define LDW(WA, WB, K) \
    WA = ((const float4*)(wp0 + (K) * 2048))[0]; \
    WB = ((const float4*)(wp0 + (K) * 2048))[1];

// ---------------------------------------------------------------- main
// LDS map:
//   [0,8192)       spk buffer 0 (f16 x 8 rows per neuron, 16B @ 16k)
//   [8192,16384)   spk buffer 1 (ping-pong)
//   [16384,32768)  stg: 16KB scratch — state staging / rates rl / out staging
__global__ __launch_bounds__(512, 1)
void lsm_main(
    const float* __restrict__ rates, const float* __restrict__ inW,
    const float* __restrict__ vin,   const float* __restrict__ cin,
    const int* __restrict__ nsteps_p,
    const uint32_t* __restrict__ ws, float* __restrict__ out)
{
    __shared__ __align__(16) unsigned char smem[2 * SPK_BUF + 16384];
    float* stg = (float*)(smem + 2 * SPK_BUF);
    float* rl  = stg;

    int q    = threadIdx.x;
    int blk  = blockIdx.x;
    int r0   = blk * R_PB;
    int w    = q >> 6;
    int lane = q & 63;
    // SIMD balance: waves {s, s+4} share SIMD s; give them groups {s, 7-s}
    int wg   = (w < 4) ? w : (11 - w);
    int n    = (int)ws[(WS_PERM >> 2) + wg * 64 + lane];
    int cw   = (int)ws[(WS_CNTW >> 2) + wg];     // wave-uniform
    int nit  = cw >> 3;                          // 8-entry chunks (<=12)
    const char* ip0 = (const char*)ws + WS_IDX + ws[(WS_IBASE >> 2) + wg]
                    + lane * 16;
    const char* wp0 = (const char*)ws + WS_WT  + ws[(WS_WBASE >> 2) + wg]
                    + lane * 32;
    int spk_n = SPK_OFF(n);                      // this column's record

    // ---- coalesced state staging: cin then vin through LDS ----
    float c0v[R_PB], v0v[R_PB];
    #pragma unroll
    for (int r = 0; r < R_PB; ++r)
        stg[r * N_NEU + q] = cin[(size_t)(r0 + r) * N_NEU + q];   // coalesced
    __syncthreads();
    #pragma unroll
    for (int r = 0; r < R_PB; ++r) c0v[r] = stg[r * N_NEU + n];
    __syncthreads();
    #pragma unroll
    for (int r = 0; r < R_PB; ++r)
        stg[r * N_NEU + q] = vin[(size_t)(r0 + r) * N_NEU + q];   // coalesced
    __syncthreads();
    #pragma unroll
    for (int r = 0; r < R_PB; ++r) v0v[r] = stg[r * N_NEU + n];
    __syncthreads();

    // ---- rates -> rl (coalesced), then I-dot (r18-proven LDS broadcast) ----
    ((float4*)rl)[q] = ((const float4*)(rates + (size_t)r0 * D_IN))[q];
    __syncthreads();

    float I[R_PB] = {0.f, 0.f, 0.f, 0.f, 0.f, 0.f, 0.f, 0.f};
    {
        const float4* wrow = (const float4*)(inW + (size_t)n * D_IN);
        for (int d4 = 0; d4 < D_IN / 4; ++d4) {
            float4 wv = wrow[d4];
            #pragma unroll
            for (int r = 0; r < R_PB; ++r) {
                const float* rr = rl + r * D_IN + d4 * 4;   // LDS broadcast
                I[r] += wv.x * rr[0] + wv.y * rr[1] + wv.z * rr[2] + wv.w * rr[3];
            }
        }
    }

    // initial f16 spikes -> buffer 0
    uint4 sini = make_uint4(0u, 0u, 0u, 0u);
    #pragma unroll
    for (int r = 0; r < R_PB; ++r) {
        unsigned hb = (c0v[r] > 0.f) ? H16_ONE : 0u;
        unsigned sh = (r & 1) ? 16 : 0;
        if (r < 2)      sini.x |= hb << sh;
        else if (r < 4) sini.y |= hb << sh;
        else if (r < 6) sini.z |= hb << sh;
        else            sini.w |= hb << sh;
    }
    *(uint4*)(smem + spk_n) = sini;

    // packed spike counters: byte r = count of (v>0) for row r (<=64, fits)
    unsigned ssx = 0u, ssy = 0u;

    // preload ENTIRE index stream into registers (constant across steps)
    uint4 xr0, xr1, xr2, xr3, xr4, xr5, xr6, xr7, xr8, xr9, xr10, xr11;
    const uint4 xz = make_uint4(0u, 0u, 0u, 0u);
    xr0  =              *(const uint4*)(ip0);
    xr1  = (1  < nit) ? *(const uint4*)(ip0 + 1024)  : xz;
    xr2  = (2  < nit) ? *(const uint4*)(ip0 + 2048)  : xz;
    xr3  = (3  < nit) ? *(const uint4*)(ip0 + 3072)  : xz;
    xr4  = (4  < nit) ? *(const uint4*)(ip0 + 4096)  : xz;
    xr5  = (5  < nit) ? *(const uint4*)(ip0 + 5120)  : xz;
    xr6  = (6  < nit) ? *(const uint4*)(ip0 + 6144)  : xz;
    xr7  = (7  < nit) ? *(const uint4*)(ip0 + 7168)  : xz;
    xr8  = (8  < nit) ? *(const uint4*)(ip0 + 8192)  : xz;
    xr9  = (9  < nit) ? *(const uint4*)(ip0 + 9216)  : xz;
    xr10 = (10 < nit) ? *(const uint4*)(ip0 + 10240) : xz;
    xr11 = (11 < nit) ? *(const uint4*)(ip0 + 11264) : xz;

    const float AS   = (float)0.8187307530779818;   // exp(-1/5)
    const float OMAS = (float)(1.0 - 0.8187307530779818);
    const float AM   = (float)0.9512294245007140;   // exp(-1/20)
    const float OMAM = (float)(1.0 - 0.9512294245007140);

    int T = nsteps_p[0];
    __syncthreads();   // initial spikes visible

    #pragma unroll 1
    for (int t = 0; t < T; ++t) {
        const unsigned char* sb = smem + ((t & 1) ? SPK_BUF : 0);   // read buf
        unsigned char*       db = smem + ((t & 1) ? 0 : SPK_BUF);   // write buf

        float rec0 = 0.f, rec1 = 0.f, rec2 = 0.f, rec3 = 0.f;
        float rec4 = 0.f, rec5 = 0.f, rec6 = 0.f, rec7 = 0.f;
        uint4 a0, a1, a2, a3, a4, a5, a6, a7;
        uint4 b0, b1, b2, b3, b4, b5, b6, b7;
        float4 waA, wbA, waB, wbB;

        // 2-deep pipeline: gather addrs from registers, weights 2-deep.
        LDW(waA, wbA, 0)
        GATH(a, xr0, sb)
        if (1 < nit)  { LDW(waB, wbB, 1)  GATH(b, xr1, sb)  }
        CONS(a, waA, wbA)
        if (1 < nit)  {
            if (2 < nit)  { LDW(waA, wbA, 2)  GATH(a, xr2, sb)  }
            CONS(b, waB, wbB)
        }
        if (2 < nit)  {
            if (3 < nit)  { LDW(waB, wbB, 3)  GATH(b, xr3, sb)  }
            CONS(a, waA, wbA)
        }
        if (3 < nit)  {
            if (4 < nit)  { LDW(waA, wbA, 4)  GATH(a, xr4, sb)  }
            CONS(b, waB, wbB)
        }
        if (4 < nit)  {
            if (5 < nit)  { LDW(waB, wbB, 5)  GATH(b, xr5, sb)  }
            CONS(a, waA, wbA)
        }
        if (5 < nit)  {
            if (6 < nit)  { LDW(waA, wbA, 6)  GATH(a, xr6, sb)  }
            CONS(b, waB, wbB)
        }
        if (6 < nit)  {
            if (7 < nit)  { LDW(waB, wbB, 7)  GATH(b, xr7, sb)  }
            CONS(a, waA, wbA)
        }
        if (7 < nit)  {
            if (8 < nit)  { LDW(waA, wbA, 8)  GATH(a, xr8, sb)  }
            CONS(b, waB, wbB)
        }
        if (8 < nit)  {
            if (9 < nit)  { LDW(waB, wbB, 9)  GATH(b, xr9, sb)  }
            CONS(a, waA, wbA)
        }
        if (9 < nit)  {
            if (10 < nit) { LDW(waA, wbA, 10) GATH(a, xr10, sb) }
            CONS(b, waB, wbB)
        }
        if (10 < nit) {
            if (11 < nit) { LDW(waB, wbB, 11) GATH(b, xr11, sb) }
            CONS(a, waA, wbA)
        }
        if (11 < nit) {
            CONS(b, waB, wbB)
        }

        // update; write new f16 spikes to the other buffer (no WAR hazard)
        uint4 ns = make_uint4(0u, 0u, 0u, 0u);
        unsigned vbx = 0u, vby = 0u;
        {
            float rca[R_PB] = {rec0, rec1, rec2, rec3, rec4, rec5, rec6, rec7};
            #pragma unroll
            for (int r = 0; r < R_PB; ++r) {
                c0v[r] = AS * c0v[r] + OMAS * (I[r] + rca[r]);
                v0v[r] = AM * v0v[r] + OMAM * c0v[r];
                unsigned hb = (c0v[r] > 0.f) ? H16_ONE : 0u;
                unsigned vb = (v0v[r] > 0.f) ? 1u : 0u;
                unsigned sh = (r & 1) ? 16 : 0;
                if (r < 2)      ns.x |= hb << sh;
                else if (r < 4) ns.y |= hb << sh;
                else if (r < 6) ns.z |= hb << sh;
                else            ns.w |= hb << sh;
                if (r < 4) vbx |= vb << (r * 8);
                else       vby |= vb << ((r - 4) * 8);
            }
        }
        ssx += vbx;   // bytewise counters, max 64 < 256: no inter-byte carry
        ssy += vby;
        *(uint4*)(db + spk_n) = ns;
        __syncthreads();   // new spikes visible; old buffer free for reuse
    }

    // ---- coalesced epilogue: stage each quantity through LDS ----
    float invT = 1.0f / (float)T;
    size_t BN = (size_t)B_ROWS * N_NEU;

    #pragma unroll
    for (int r = 0; r < R_PB; ++r) {
        unsigned cnt = (r < 4) ? ((ssx >> (r * 8)) & 0xffu)
                               : ((ssy >> ((r - 4) * 8)) & 0xffu);
        stg[r * N_NEU + n] = (float)cnt * invT;
    }
    __syncthreads();
    #pragma unroll
    for (int r = 0; r < R_PB; ++r)
        out[(size_t)(r0 + r) * N_NEU + q] = stg[r * N_NEU + q];   // coalesced
    __syncthreads();

    #pragma unroll
    for (int r = 0; r < R_PB; ++r) stg[r * N_NEU + n] = v0v[r];
    __syncthreads();
    #pragma unroll
    for (int r = 0; r < R_PB; ++r)
        out[BN + (size_t)(r0 + r) * N_NEU + q] = stg[r * N_NEU + q];
    __syncthreads();

    #pragma unroll
    for (int r = 0; r < R_PB; ++r) stg[r * N_NEU + n] = c0v[r];
    __syncthreads();
    #pragma unroll
    for (int r = 0; r < R_PB; ++r)
        out[2 * BN + (size_t)(r0 + r) * N_NEU + q] = stg[r * N_NEU + q];
}

// ---------------------------------------------------------------- launch
extern "C" void kernel_launch(void* const* d_in, const int* in_sizes, int n_in,
                              void* d_out, int out_size, void* d_ws, size_t ws_size,
                              hipStream_t stream)
{
    const float* rates = (const float*)d_in[0];
    const float* inW   = (const float*)d_in[1];
    const float* W     = (const float*)d_in[2];
    const float* vin   = (const float*)d_in[3];
    const float* cin   = (const float*)d_in[4];
    const int*   nst   = (const int*)d_in[5];
    uint32_t* ws = (uint32_t*)d_ws;
    float* out = (float*)d_out;
    (void)in_sizes; (void)n_in; (void)out_size; (void)ws_size;

    // zero CNT (harness poisons d_ws to 0xAA before every call)
    hipMemsetAsync((char*)d_ws + WS_CNT, 0, 2048, stream);

    lsm_count<<<128, 256, 0, stream>>>(W, ws);
    lsm_sort<<<1, 512, 0, stream>>>(ws);
    lsm_fill<<<8, 512, 0, stream>>>(W, ws);
    lsm_main<<<NBLK, 512, 0, stream>>>(rates, inW, vin, cin, nst, ws, out);
}

// Round 3
// 378.643 us; speedup vs baseline: 1.6570x; 1.6570x over previous
//
#include <hip/hip_runtime.h>
#include <stdint.h>

// LiquidStateMachine on MI355X — round 21.
// r19/r20 post-mortem: the ~310us was the dynamic per-slot LPT scheduler
// itself (1 wave, zero latency hiding, LDS-atomic return latency + retry
// divergence fully exposed). It costs 4x what it could save. KILLED.
// r21 insight: the OPTIMAL schedule is STATIC. Gather cost per b128 slot =
// max_cluster(#distinct addrs), floor 8 (64 lanes / 8 four-bank clusters).
// Designate lane ls at slot j to cluster c=(j+ls)&7: every slot gets
// EXACTLY 8 lanes per cluster -> <=8 distinct per cluster -> floor cost
// ALWAYS (pads read the designated cluster's shared addr, still <=8
// distinct). Each column fills its designated slots from its k&7 buckets
// (quota Q=cw/8), spills rare overflow (P(bucket>Q)~1.3%) into free slots
// (cost 9 on those few instrs), pads the rest. Zero coordination: one
// thread owns one column end-to-end; no atomics, no barriers.
// lsm_fill v3: 8 blk x 512 thr; batch-8 coalesced W sweep (loads pipeline);
// per-thread buckets in LDS; static emission. ~310 -> ~25us.
// lsm_main BYTE-IDENTICAL to r18/r20 -> schedule effect finally isolated.
// Weights EXACT fp32 (r2: rounding flips spikes); f16 spike 0/1 exact.
//
// d_ws layout (bytes):
//   0      PERM[512]  sorted-rank -> column
//   2048   RANK[512]  column -> sorted rank
//   4096   CNT[512]   nnz per column          (zeroed via hipMemsetAsync)
//   8192   CNTW[8]    per-group padded trip count (multiple of 8)
//   8256   IBASE[8]   per-group byte base into IDX region
//   8320   WBASE[8]   per-group byte base into WT region
//   16384  IDX        u16 spike-offset (16k):
//                     byte = ib + (j>>3)*1024 + lane*16 + (j&7)*2
//   81920  WT         f32 w: byte = wb + (j>>3)*2048 + lane*32 + (j&7)*4

#define N_NEU 512
#define B_ROWS 2048
#define D_IN 256
#define R_PB 8
#define NBLK (B_ROWS / R_PB)   // 256 blocks x 512 threads = 1 block/CU

#define WS_PERM    0
#define WS_RANK    2048
#define WS_CNT     4096
#define WS_CNTW    8192
#define WS_IBASE   8256
#define WS_WBASE   8320
#define WS_IDX     16384
#define WS_WT      81920

// spike record: 16 bytes (8 rows x f16 0/1) at natural offset 16k
#define SPK_OFF(k)  ((k) << 4)
#define SPK_BUF     8192       // one buffer: 512 neurons x 16 B

#define H16_ONE 0x3C00u        // f16 1.0
#define MAXPC   24             // max entries per (column, cluster); mean 6.4

// ---------------------------------------------------------------- prep A
__global__ __launch_bounds__(256) void lsm_count(
    const float* __restrict__ W, uint32_t* __restrict__ ws)
{
    int t  = threadIdx.x;
    int k0 = blockIdx.x * 4;
    int c0 = 0, c1 = 0;
    #pragma unroll
    for (int kk = 0; kk < 4; ++kk) {
        const float* row = W + (size_t)(k0 + kk) * N_NEU;
        c0 += (row[t]       != 0.0f) ? 1 : 0;
        c1 += (row[t + 256] != 0.0f) ? 1 : 0;
    }
    if (c0) atomicAdd(&ws[(WS_CNT >> 2) + t],       (uint32_t)c0);
    if (c1) atomicAdd(&ws[(WS_CNT >> 2) + t + 256], (uint32_t)c1);
}

// ---------------------------------------------------------------- prep B
__global__ __launch_bounds__(512) void lsm_sort(uint32_t* __restrict__ ws)
{
    __shared__ int hist[N_NEU + 1];
    __shared__ int csort[N_NEU];
    __shared__ int gcw[8];

    int t = threadIdx.x;
    int creal = (int)ws[(WS_CNT >> 2) + t];
    for (int i = t; i < N_NEU + 1; i += 512) hist[i] = 0;
    __syncthreads();
    atomicAdd(&hist[creal], 1);
    __syncthreads();
    if (t == 0) {
        int acc = 0;
        for (int v = 0; v <= N_NEU; ++v) { int h = hist[v]; hist[v] = acc; acc += h; }
    }
    __syncthreads();
    int rank = atomicAdd(&hist[creal], 1);
    ws[(WS_PERM >> 2) + rank] = (uint32_t)t;
    ws[(WS_RANK >> 2) + t]    = (uint32_t)rank;
    csort[rank] = creal;
    __syncthreads();
    if (t < 8) {
        int cw = csort[t * 64 + 63];         // ascending -> group max is last
        cw = (cw + 7) & ~7;                  // pad to multiple of 8 (one chunk)
        gcw[t] = cw;
        ws[(WS_CNTW >> 2) + t] = (uint32_t)cw;
    }
    __syncthreads();
    if (t == 0) {
        int ai = 0, aw = 0;
        for (int g = 0; g < 8; ++g) {
            ws[(WS_IBASE >> 2) + g] = (uint32_t)ai;
            ws[(WS_WBASE >> 2) + g] = (uint32_t)aw;
            ai += gcw[g] * 64 * 2;           // bytes (u16 per entry)
            aw += gcw[g] * 64 * 4;           // bytes (f32 per entry)
        }
    }
    // fill writes EVERY slot (pads interleaved by the static schedule)
}

// ---------------------------------------------------------------- prep C
// One block per GROUP (8 blocks x 512 threads). Thread t owns column t
// start-to-finish: coalesced batch-8 W sweep buckets nonzero k by cluster
// k&7 into LDS; then the 64 "mine" threads emit the static round-robin
// schedule (designated cluster (j+ls)&7, quota Q=cw/8 per bucket, overflow
// spills into free slots, pads read designated cluster's shared addr).
// No atomics, no barriers, fully deterministic.
__global__ __launch_bounds__(512) void lsm_fill(
    const float* __restrict__ W, uint32_t* __restrict__ ws)
{
    int g = blockIdx.x;             // 8 groups
    int t = threadIdx.x;            // 512: thread t = column t
    char* base = (char*)ws;

    __shared__ unsigned short ent_k[64][8][MAXPC];  // 24 KB
    __shared__ float          ent_w[64][8][MAXPC];  // 48 KB

    int rank = (int)ws[(WS_RANK >> 2) + t];
    int ls   = rank & 63;
    bool mine = ((rank >> 6) == g);

    // ---- discovery: batch 8 loads (pipelined), then process ----
    unsigned cl = 0, ch = 0;        // packed per-cluster byte counters
    for (int k0 = 0; k0 < N_NEU; k0 += 8) {
        float wv[8];
        #pragma unroll
        for (int rr = 0; rr < 8; ++rr)
            wv[rr] = W[(size_t)(k0 + rr) * N_NEU + t];   // coalesced
        #pragma unroll
        for (int rr = 0; rr < 8; ++rr) {
            if (mine && wv[rr] != 0.0f) {
                unsigned cnt = ((rr < 4) ? (cl >> (rr * 8))
                                         : (ch >> ((rr - 4) * 8))) & 0xffu;
                ent_k[ls][rr][cnt] = (unsigned short)(k0 + rr);
                ent_w[ls][rr][cnt] = wv[rr];
                if (rr < 4) cl += 1u << (rr * 8);
                else        ch += 1u << ((rr - 4) * 8);
            }
        }
    }
    // no barrier: each thread reads only its own ent_k/ent_w[ls]

    // ---- static emission (only the 64 owning threads) ----
    if (mine) {
        int cw = (int)ws[(WS_CNTW >> 2) + g];   // multiple of 8, <= 96
        uint32_t ib = ws[(WS_IBASE >> 2) + g];
        uint32_t wb = ws[(WS_WBASE >> 2) + g];
        int Q = cw >> 3;                        // designated quota per bucket

        unsigned ul = 0, uh = 0;                // packed used counters
        // overflow iterator: bucket ovr, entry index ovi (>= Q)
        int ovr = 0, ovi = Q;
        while (ovr < 8) {
            int nr = (int)(((ovr < 4) ? (cl >> (ovr * 8))
                                      : (ch >> ((ovr - 4) * 8))) & 0xffu);
            if (ovi < nr) break;
            ++ovr; ovi = Q;
        }

        for (int j = 0; j < cw; ++j) {
            int c = (j + ls) & 7;               // designated cluster
            int nc = (int)(((c < 4) ? (cl >> (c * 8))
                                    : (ch >> ((c - 4) * 8))) & 0xffu);
            int uc = (int)(((c < 4) ? (ul >> (c * 8))
                                    : (uh >> ((c - 4) * 8))) & 0xffu);
            int dc = (nc < Q) ? nc : Q;         // designated count
            unsigned short idxv; float wvv;
            if (uc < dc) {
                idxv = (unsigned short)SPK_OFF(ent_k[ls][c][uc]);
                wvv  = ent_w[ls][c][uc];
                if (c < 4) ul += 1u << (c * 8);
                else       uh += 1u << ((c - 4) * 8);
            } else if (ovr < 8) {
                idxv = (unsigned short)SPK_OFF(ent_k[ls][ovr][ovi]);
                wvv  = ent_w[ls][ovr][ovi];
                ++ovi;
                while (ovr < 8) {
                    int nr = (int)(((ovr < 4) ? (cl >> (ovr * 8))
                                              : (ch >> ((ovr - 4) * 8))) & 0xffu);
                    if (ovi < nr) break;
                    ++ovr; ovi = Q;
                }
            } else {
                idxv = (unsigned short)SPK_OFF(c);   // pad: shared addr in c
                wvv  = 0.0f;
            }
            *(unsigned short*)(base + WS_IDX + ib + (j >> 3) * 1024 + ls * 16 + (j & 7) * 2) = idxv;
            *(float*)(base + WS_WT + wb + (j >> 3) * 2048 + ls * 32 + (j & 7) * 4) = wvv;
        }
    }
}

// -------- spill-proof pipeline macros (all scalars, no arrays/fns) --------
// B = spike-buffer base for this step; offsets pre-scaled to 16k.
#define GATH(P, X, B) \
    P##0 = *(const uint4*)((B) + ((X).x & 0xffffu)); \
    P##1 = *(const uint4*)((B) + ((X).x >> 16));     \
    P##2 = *(const uint4*)((B) + ((X).y & 0xffffu)); \
    P##3 = *(const uint4*)((B) + ((X).y >> 16));     \
    P##4 = *(const uint4*)((B) + ((X).z & 0xffffu)); \
    P##5 = *(const uint4*)((B) + ((X).z >> 16));     \
    P##6 = *(const uint4*)((B) + ((X).w & 0xffffu)); \
    P##7 = *(const uint4*)((B) + ((X).w >> 16));

// mixed-precision FMA: acc(f32) += w(f32) * f16 half of S (lo/hi)
#define FMIX_LO(ACC, WV, S) \
    asm("v_fma_mix_f32 %0, %1, %2, %0 op_sel:[0,0,0] op_sel_hi:[0,1,0]" \
        : "+v"(ACC) : "v"(WV), "v"(S));
#define FMIX_HI(ACC, WV, S) \
    asm("v_fma_mix_f32 %0, %1, %2, %0 op_sel:[0,1,0] op_sel_hi:[0,1,0]" \
        : "+v"(ACC) : "v"(WV), "v"(S));

// one entry: weight WV x 8 rows' f16 spikes (uint4 S = 4 f16-pairs)
#define C1(S, WV) \
    FMIX_LO(rec0, WV, (S).x) FMIX_HI(rec1, WV, (S).x) \
    FMIX_LO(rec2, WV, (S).y) FMIX_HI(rec3, WV, (S).y) \
    FMIX_LO(rec4, WV, (S).z) FMIX_HI(rec5, WV, (S).z) \
    FMIX_LO(rec6, WV, (S).w) FMIX_HI(rec7, WV, (S).w)

#define CONS(P, WA, WB) \
    C1(P##0, (WA).x) C1(P##1, (WA).y) C1(P##2, (WA).z) C1(P##3, (WA).w) \
    C1(P##4, (WB).x) C1(P##5, (WB).y) C1(P##6, (WB).z) C1(P##7, (WB).w)

#define LDW(WA, WB, K) \
    WA = ((const float4*)(wp0 + (K) * 2048))[0]; \
    WB = ((const float4*)(wp0 + (K) * 2048))[1];

// ---------------------------------------------------------------- main
// LDS map:
//   [0,8192)       spk buffer 0 (f16 x 8 rows per neuron, 16B @ 16k)
//   [8192,16384)   spk buffer 1 (ping-pong)
//   [16384,32768)  stg: 16KB scratch — state staging / rates rl / out staging
__global__ __launch_bounds__(512, 1)
void lsm_main(
    const float* __restrict__ rates, const float* __restrict__ inW,
    const float* __restrict__ vin,   const float* __restrict__ cin,
    const int* __restrict__ nsteps_p,
    const uint32_t* __restrict__ ws, float* __restrict__ out)
{
    __shared__ __align__(16) unsigned char smem[2 * SPK_BUF + 16384];
    float* stg = (float*)(smem + 2 * SPK_BUF);
    float* rl  = stg;

    int q    = threadIdx.x;
    int blk  = blockIdx.x;
    int r0   = blk * R_PB;
    int w    = q >> 6;
    int lane = q & 63;
    // SIMD balance: waves {s, s+4} share SIMD s; give them groups {s, 7-s}
    int wg   = (w < 4) ? w : (11 - w);
    int n    = (int)ws[(WS_PERM >> 2) + wg * 64 + lane];
    int cw   = (int)ws[(WS_CNTW >> 2) + wg];     // wave-uniform
    int nit  = cw >> 3;                          // 8-entry chunks (<=12)
    const char* ip0 = (const char*)ws + WS_IDX + ws[(WS_IBASE >> 2) + wg]
                    + lane * 16;
    const char* wp0 = (const char*)ws + WS_WT  + ws[(WS_WBASE >> 2) + wg]
                    + lane * 32;
    int spk_n = SPK_OFF(n);                      // this column's record

    // ---- coalesced state staging: cin then vin through LDS ----
    float c0v[R_PB], v0v[R_PB];
    #pragma unroll
    for (int r = 0; r < R_PB; ++r)
        stg[r * N_NEU + q] = cin[(size_t)(r0 + r) * N_NEU + q];   // coalesced
    __syncthreads();
    #pragma unroll
    for (int r = 0; r < R_PB; ++r) c0v[r] = stg[r * N_NEU + n];
    __syncthreads();
    #pragma unroll
    for (int r = 0; r < R_PB; ++r)
        stg[r * N_NEU + q] = vin[(size_t)(r0 + r) * N_NEU + q];   // coalesced
    __syncthreads();
    #pragma unroll
    for (int r = 0; r < R_PB; ++r) v0v[r] = stg[r * N_NEU + n];
    __syncthreads();

    // ---- rates -> rl (coalesced), then I-dot (LDS broadcast) ----
    ((float4*)rl)[q] = ((const float4*)(rates + (size_t)r0 * D_IN))[q];
    __syncthreads();

    float I[R_PB] = {0.f, 0.f, 0.f, 0.f, 0.f, 0.f, 0.f, 0.f};
    {
        const float4* wrow = (const float4*)(inW + (size_t)n * D_IN);
        for (int d4 = 0; d4 < D_IN / 4; ++d4) {
            float4 wv = wrow[d4];
            #pragma unroll
            for (int r = 0; r < R_PB; ++r) {
                const float* rr = rl + r * D_IN + d4 * 4;   // LDS broadcast
                I[r] += wv.x * rr[0] + wv.y * rr[1] + wv.z * rr[2] + wv.w * rr[3];
            }
        }
    }

    // initial f16 spikes -> buffer 0
    uint4 sini = make_uint4(0u, 0u, 0u, 0u);
    #pragma unroll
    for (int r = 0; r < R_PB; ++r) {
        unsigned hb = (c0v[r] > 0.f) ? H16_ONE : 0u;
        unsigned sh = (r & 1) ? 16 : 0;
        if (r < 2)      sini.x |= hb << sh;
        else if (r < 4) sini.y |= hb << sh;
        else if (r < 6) sini.z |= hb << sh;
        else            sini.w |= hb << sh;
    }
    *(uint4*)(smem + spk_n) = sini;

    // packed spike counters: byte r = count of (v>0) for row r (<=64, fits)
    unsigned ssx = 0u, ssy = 0u;

    // preload ENTIRE index stream into registers (constant across steps)
    uint4 xr0, xr1, xr2, xr3, xr4, xr5, xr6, xr7, xr8, xr9, xr10, xr11;
    const uint4 xz = make_uint4(0u, 0u, 0u, 0u);
    xr0  =              *(const uint4*)(ip0);
    xr1  = (1  < nit) ? *(const uint4*)(ip0 + 1024)  : xz;
    xr2  = (2  < nit) ? *(const uint4*)(ip0 + 2048)  : xz;
    xr3  = (3  < nit) ? *(const uint4*)(ip0 + 3072)  : xz;
    xr4  = (4  < nit) ? *(const uint4*)(ip0 + 4096)  : xz;
    xr5  = (5  < nit) ? *(const uint4*)(ip0 + 5120)  : xz;
    xr6  = (6  < nit) ? *(const uint4*)(ip0 + 6144)  : xz;
    xr7  = (7  < nit) ? *(const uint4*)(ip0 + 7168)  : xz;
    xr8  = (8  < nit) ? *(const uint4*)(ip0 + 8192)  : xz;
    xr9  = (9  < nit) ? *(const uint4*)(ip0 + 9216)  : xz;
    xr10 = (10 < nit) ? *(const uint4*)(ip0 + 10240) : xz;
    xr11 = (11 < nit) ? *(const uint4*)(ip0 + 11264) : xz;

    const float AS   = (float)0.8187307530779818;   // exp(-1/5)
    const float OMAS = (float)(1.0 - 0.8187307530779818);
    const float AM   = (float)0.9512294245007140;   // exp(-1/20)
    const float OMAM = (float)(1.0 - 0.9512294245007140);

    int T = nsteps_p[0];
    __syncthreads();   // initial spikes visible

    #pragma unroll 1
    for (int t = 0; t < T; ++t) {
        const unsigned char* sb = smem + ((t & 1) ? SPK_BUF : 0);   // read buf
        unsigned char*       db = smem + ((t & 1) ? 0 : SPK_BUF);   // write buf

        float rec0 = 0.f, rec1 = 0.f, rec2 = 0.f, rec3 = 0.f;
        float rec4 = 0.f, rec5 = 0.f, rec6 = 0.f, rec7 = 0.f;
        uint4 a0, a1, a2, a3, a4, a5, a6, a7;
        uint4 b0, b1, b2, b3, b4, b5, b6, b7;
        float4 waA, wbA, waB, wbB;

        // 2-deep pipeline: gather addrs from registers, weights 2-deep.
        LDW(waA, wbA, 0)
        GATH(a, xr0, sb)
        if (1 < nit)  { LDW(waB, wbB, 1)  GATH(b, xr1, sb)  }
        CONS(a, waA, wbA)
        if (1 < nit)  {
            if (2 < nit)  { LDW(waA, wbA, 2)  GATH(a, xr2, sb)  }
            CONS(b, waB, wbB)
        }
        if (2 < nit)  {
            if (3 < nit)  { LDW(waB, wbB, 3)  GATH(b, xr3, sb)  }
            CONS(a, waA, wbA)
        }
        if (3 < nit)  {
            if (4 < nit)  { LDW(waA, wbA, 4)  GATH(a, xr4, sb)  }
            CONS(b, waB, wbB)
        }
        if (4 < nit)  {
            if (5 < nit)  { LDW(waB, wbB, 5)  GATH(b, xr5, sb)  }
            CONS(a, waA, wbA)
        }
        if (5 < nit)  {
            if (6 < nit)  { LDW(waA, wbA, 6)  GATH(a, xr6, sb)  }
            CONS(b, waB, wbB)
        }
        if (6 < nit)  {
            if (7 < nit)  { LDW(waB, wbB, 7)  GATH(b, xr7, sb)  }
            CONS(a, waA, wbA)
        }
        if (7 < nit)  {
            if (8 < nit)  { LDW(waA, wbA, 8)  GATH(a, xr8, sb)  }
            CONS(b, waB, wbB)
        }
        if (8 < nit)  {
            if (9 < nit)  { LDW(waB, wbB, 9)  GATH(b, xr9, sb)  }
            CONS(a, waA, wbA)
        }
        if (9 < nit)  {
            if (10 < nit) { LDW(waA, wbA, 10) GATH(a, xr10, sb) }
            CONS(b, waB, wbB)
        }
        if (10 < nit) {
            if (11 < nit) { LDW(waB, wbB, 11) GATH(b, xr11, sb) }
            CONS(a, waA, wbA)
        }
        if (11 < nit) {
            CONS(b, waB, wbB)
        }

        // update; write new f16 spikes to the other buffer (no WAR hazard)
        uint4 ns = make_uint4(0u, 0u, 0u, 0u);
        unsigned vbx = 0u, vby = 0u;
        {
            float rca[R_PB] = {rec0, rec1, rec2, rec3, rec4, rec5, rec6, rec7};
            #pragma unroll
            for (int r = 0; r < R_PB; ++r) {
                c0v[r] = AS * c0v[r] + OMAS * (I[r] + rca[r]);
                v0v[r] = AM * v0v[r] + OMAM * c0v[r];
                unsigned hb = (c0v[r] > 0.f) ? H16_ONE : 0u;
                unsigned vb = (v0v[r] > 0.f) ? 1u : 0u;
                unsigned sh = (r & 1) ? 16 : 0;
                if (r < 2)      ns.x |= hb << sh;
                else if (r < 4) ns.y |= hb << sh;
                else if (r < 6) ns.z |= hb << sh;
                else            ns.w |= hb << sh;
                if (r < 4) vbx |= vb << (r * 8);
                else       vby |= vb << ((r - 4) * 8);
            }
        }
        ssx += vbx;   // bytewise counters, max 64 < 256: no inter-byte carry
        ssy += vby;
        *(uint4*)(db + spk_n) = ns;
        __syncthreads();   // new spikes visible; old buffer free for reuse
    }

    // ---- coalesced epilogue: stage each quantity through LDS ----
    float invT = 1.0f / (float)T;
    size_t BN = (size_t)B_ROWS * N_NEU;

    #pragma unroll
    for (int r = 0; r < R_PB; ++r) {
        unsigned cnt = (r < 4) ? ((ssx >> (r * 8)) & 0xffu)
                               : ((ssy >> ((r - 4) * 8)) & 0xffu);
        stg[r * N_NEU + n] = (float)cnt * invT;
    }
    __syncthreads();
    #pragma unroll
    for (int r = 0; r < R_PB; ++r)
        out[(size_t)(r0 + r) * N_NEU + q] = stg[r * N_NEU + q];   // coalesced
    __syncthreads();

    #pragma unroll
    for (int r = 0; r < R_PB; ++r) stg[r * N_NEU + n] = v0v[r];
    __syncthreads();
    #pragma unroll
    for (int r = 0; r < R_PB; ++r)
        out[BN + (size_t)(r0 + r) * N_NEU + q] = stg[r * N_NEU + q];
    __syncthreads();

    #pragma unroll
    for (int r = 0; r < R_PB; ++r) stg[r * N_NEU + n] = c0v[r];
    __syncthreads();
    #pragma unroll
    for (int r = 0; r < R_PB; ++r)
        out[2 * BN + (size_t)(r0 + r) * N_NEU + q] = stg[r * N_NEU + q];
}

// ---------------------------------------------------------------- launch
extern "C" void kernel_launch(void* const* d_in, const int* in_sizes, int n_in,
                              void* d_out, int out_size, void* d_ws, size_t ws_size,
                              hipStream_t stream)
{
    const float* rates = (const float*)d_in[0];
    const float* inW   = (const float*)d_in[1];
    const float* W     = (const float*)d_in[2];
    const float* vin   = (const float*)d_in[3];
    const float* cin   = (const float*)d_in[4];
    const int*   nst   = (const int*)d_in[5];
    uint32_t* ws = (uint32_t*)d_ws;
    float* out = (float*)d_out;
    (void)in_sizes; (void)n_in; (void)out_size; (void)ws_size;

    // zero CNT (harness poisons d_ws to 0xAA before every call)
    hipMemsetAsync((char*)d_ws + WS_CNT, 0, 2048, stream);

    lsm_count<<<128, 256, 0, stream>>>(W, ws);
    lsm_sort<<<1, 512, 0, stream>>>(ws);
    lsm_fill<<<8, 512, 0, stream>>>(W, ws);
    lsm_main<<<NBLK, 512, 0, stream>>>(rates, inW, vin, cin, nst, ws, out);
}